// Round 7
// baseline (157.172 us; speedup 1.0000x reference)
//
#include <hip/hip_runtime.h>

#define BATCH  4096
#define NROWS  8192
#define LATENT 2048
#define ZDIM   128
#define PRIORc       0.3f
#define PRIOR_PRIMEc 0.5f
// sqrt(2 * log2(e)): folds both 1/TEMP and the ln->log2 conversion into zn,
// so exp(sim/TEMP) == exp2(dot of scaled vectors) -> bare v_exp_f32.
#define ZSCALE 1.6986436f

typedef __attribute__((ext_vector_type(8))) short bf16x8;  // 8 bf16 = 4 VGPRs
typedef __attribute__((ext_vector_type(4))) float f32x4;   // MFMA C/D + NT loads

__device__ inline unsigned short f2bf_rne(float f) {
    unsigned int u = __float_as_uint(f);
    u = u + 0x7fffu + ((u >> 16) & 1u);
    return (unsigned short)(u >> 16);
}
__device__ inline float bf2f(unsigned short h) {
    return __uint_as_float(((unsigned int)h) << 16);
}
__device__ inline float wave_reduce_sum(float v) {
#pragma unroll
    for (int m = 1; m < 64; m <<= 1) v += __shfl_xor(v, m, 64);
    return v;
}

// ---------------------------------------------------------------------------
// Node 1: blocks [0,1024) = z-prep (normalize+swizzle+pos+expdiag+S_row=0),
//         blocks [1024,3072) = logits (HBM-bound, NT loads).
// Disjoint writes, both read only inputs -> safe in one kernel, co-scheduled.
// Swizzle: chunk (g*4+kt), lane q*16+(row&15) holds k = kt*32+q*8 .. +7
// NOTE: no grid-wide fences anywhere — R5 showed __threadfence() from 3072
// blocks (L2 wb+inv) thrashes znb out of L2 (5x refetch, 136->520us).
// ---------------------------------------------------------------------------
__global__ void k_prep(const float* __restrict__ z_i, const float* __restrict__ z_j,
                       unsigned short* __restrict__ znb, float* __restrict__ pos,
                       float* __restrict__ expdiag, float* __restrict__ S_row,
                       const float* __restrict__ h_i, const float* __restrict__ h_j,
                       const float* __restrict__ W, const float* __restrict__ bb,
                       float* __restrict__ logits) {
    int bid = blockIdx.x;
    int wave = threadIdx.x >> 6, lane = threadIdx.x & 63;
    if (bid < 1024) {
        int gid = bid * 256 + threadIdx.x;
        if (gid < NROWS) S_row[gid] = 0.f;

        int r = bid * 4 + wave;               // 0..4095
        int p = r + BATCH;
        float2 a = ((const float2*)(z_i + (size_t)r * ZDIM))[lane];
        float2 c = ((const float2*)(z_j + (size_t)r * ZDIM))[lane];
        float sa = wave_reduce_sum(a.x * a.x + a.y * a.y);
        float sc = wave_reduce_sum(c.x * c.x + c.y * c.y);
        float dd = wave_reduce_sum(a.x * c.x + a.y * c.y);
        float inva = 1.f / fmaxf(sqrtf(sa), 1e-8f);
        float invc = 1.f / fmaxf(sqrtf(sc), 1e-8f);
        if (lane == 0) {
            float pv = 2.0f * dd * inva * invc;   // cos-sim / TEMP, exact fp32
            pos[r] = pv;
            pos[p] = pv;
        }
        int kt = lane >> 4;
        int q  = (lane >> 2) & 3;
        int j  = (lane & 3) * 2;
        int lrow = q * 16;
        float fa = inva * ZSCALE, fc = invc * ZSCALE;
        ushort2 wa, wc;
        wa.x = f2bf_rne(a.x * fa); wa.y = f2bf_rne(a.y * fa);
        wc.x = f2bf_rne(c.x * fc); wc.y = f2bf_rne(c.y * fc);
        {   // row r (from z_i)
            size_t off = ((size_t)((r >> 4) * 4 + kt) * 64 + (lrow + (r & 15))) * 8 + j;
            *(ushort2*)(znb + off) = wa;
        }
        {   // row p (from z_j)
            size_t off = ((size_t)((p >> 4) * 4 + kt) * 64 + (lrow + (p & 15))) * 8 + j;
            *(ushort2*)(znb + off) = wc;
        }
        // self-dot of the rounded values == MFMA diagonal (log2 domain)
        float xa = bf2f(wa.x), ya = bf2f(wa.y);
        float xc = bf2f(wc.x), yc = bf2f(wc.y);
        float sda = wave_reduce_sum(xa * xa + ya * ya);
        float sdc = wave_reduce_sum(xc * xc + yc * yc);
        if (lane == 0) {
            expdiag[r] = __builtin_amdgcn_exp2f(sda);
            expdiag[p] = __builtin_amdgcn_exp2f(sdc);
        }
    } else {
        int r = (bid - 1024) * 4 + wave;
        const float* h = (r < BATCH) ? (h_i + (size_t)r * LATENT)
                                     : (h_j + (size_t)(r - BATCH) * LATENT);
        const f32x4* h4 = (const f32x4*)h;
        const f32x4* w4 = (const f32x4*)W;
        float s = 0.f;
#pragma unroll
        for (int itr = 0; itr < 8; ++itr) {
            f32x4 av = __builtin_nontemporal_load(&h4[itr * 64 + lane]);
            f32x4 wv = w4[itr * 64 + lane];
            s += av.x * wv.x + av.y * wv.y + av.z * wv.z + av.w * wv.w;
        }
        s = wave_reduce_sum(s);
        if (lane == 0) logits[r] = s + bb[0];
    }
}

// ---------------------------------------------------------------------------
// Node 2: symmetric sim. Block (bx,by) covers rows [by*128,+128) x cols
// [bx*512,+512); skipped if entirely below the diagonal at 16-granularity
// (32bx+31 < 8by) -> ~550/1024 live blocks. Each 16x16 subtile with
// g_c >= g_r computed once: row-sums always; col-sums (the transposed
// contribution) when g_c > g_r, via xor16/32 q-reduce + coalesced atomics.
// Diagonal subtile's self term subtracted later via expdiag. All masks are
// wave-uniform scalars. B frags software-pipelined; literal-zero-C MFMA;
// bare exp2 epilogue.
// ---------------------------------------------------------------------------
__global__ void __launch_bounds__(256, 3) k_sim(const unsigned short* __restrict__ znb,
                                                float* __restrict__ S_row) {
    int bx = blockIdx.x, by = blockIdx.y;
    if (bx * 32 + 31 < by * 8) return;        // fully below diagonal
    int lane = threadIdx.x & 63, wave = threadIdx.x >> 6;
    int q = lane >> 4, t = lane & 15;
    int gA = by * 8 + (wave >> 1) * 4;        // abs 16-row group base (4 mt)
    int base16 = bx * 32 + (wave & 1) * 4;    // abs 16-col group base
    const bf16x8* zf = (const bf16x8*)znb;

    bf16x8 a[4][4];
#pragma unroll
    for (int mt = 0; mt < 4; ++mt)
#pragma unroll
        for (int kt = 0; kt < 4; ++kt)
            a[mt][kt] = zf[(size_t)((gA + mt) * 4 + kt) * 64 + lane];

    float s[16];
#pragma unroll
    for (int i = 0; i < 16; ++i) s[i] = 0.f;

    bf16x8 b[4];
#pragma unroll
    for (int kt = 0; kt < 4; ++kt)
        b[kt] = zf[(size_t)(base16 * 4 + kt) * 64 + lane];

    f32x4 zero = {0.f, 0.f, 0.f, 0.f};
#pragma unroll 1
    for (int idx = 0; idx < 16; ++idx) {
        int g_c = base16 + (idx >> 2) * 8 + (idx & 3);
        bf16x8 bn[4];
        if (idx < 15) {
            int ng = base16 + ((idx + 1) >> 2) * 8 + ((idx + 1) & 3);
#pragma unroll
            for (int kt = 0; kt < 4; ++kt)
                bn[kt] = zf[(size_t)(ng * 4 + kt) * 64 + lane];
        }
        if (g_c >= gA) {                      // wave-uniform
            f32x4 acc[4];
#pragma unroll
            for (int mt = 0; mt < 4; ++mt)    // kt=0 consumes literal-zero C
                acc[mt] = __builtin_amdgcn_mfma_f32_16x16x32_bf16(a[mt][0], b[0], zero, 0, 0, 0);
#pragma unroll
            for (int kt = 1; kt < 4; ++kt)
#pragma unroll
                for (int mt = 0; mt < 4; ++mt)
                    acc[mt] = __builtin_amdgcn_mfma_f32_16x16x32_bf16(a[mt][kt], b[kt], acc[mt], 0, 0, 0);
            float ecol = 0.f;
#pragma unroll
            for (int mt = 0; mt < 4; ++mt) {
                bool rowv = (g_c >= gA + mt);
                bool colv = (g_c >  gA + mt);
                float em = 0.f;
#pragma unroll
                for (int reg = 0; reg < 4; ++reg) {
                    float e = __builtin_amdgcn_exp2f(acc[mt][reg]);
                    s[mt * 4 + reg] += rowv ? e : 0.f;
                    em += e;
                }
                ecol += colv ? em : 0.f;
            }
            if (g_c > gA) {                   // transposed contribution
                ecol += __shfl_xor(ecol, 16, 64);
                ecol += __shfl_xor(ecol, 32, 64);
                if (lane < 16) atomicAdd(&S_row[g_c * 16 + lane], ecol);
            }
        }
#pragma unroll
        for (int kt = 0; kt < 4; ++kt) b[kt] = bn[kt];
    }
#pragma unroll
    for (int i = 0; i < 16; ++i) {
        float v = s[i];
        v += __shfl_xor(v, 1, 64);
        v += __shfl_xor(v, 2, 64);
        v += __shfl_xor(v, 4, 64);
        v += __shfl_xor(v, 8, 64);
        if (t == 0) atomicAdd(&S_row[gA * 16 + (i >> 2) * 16 + q * 4 + (i & 3)], v);
    }
}

// Node 3: nnPU risk from logits+target, NT-Xent from S_row (minus the
// bf16-exact diagonal term) + pos, weighted combine.
__global__ void k_final(const float* __restrict__ S_row, const float* __restrict__ pos,
                        const float* __restrict__ expdiag,
                        const float* __restrict__ logits, const int* __restrict__ target,
                        const float* __restrict__ w_onnpu, float* __restrict__ out) {
    float nt_s = 0.f;
    for (int r = threadIdx.x; r < NROWS; r += 1024)
        nt_s += __logf(S_row[r] - expdiag[r]) - pos[r];
    float v[8];
#pragma unroll
    for (int i = 0; i < 8; ++i) v[i] = 0.f;
    for (int r = threadIdx.x; r < BATCH; r += 1024) {
        float li = logits[r], lj = logits[BATCH + r];
        bool p = (target[r] == 1);
        float si_n = 1.f / (1.f + __expf(li));
        float si_p = 1.f / (1.f + __expf(-li));
        float sj_n = 1.f / (1.f + __expf(lj));
        float sj_p = 1.f / (1.f + __expf(-lj));
        v[0] += p ? 1.f : 0.f;
        v[1] += p ? 0.f : 1.f;
        v[2] += p ? si_n : 0.f;
        v[3] += p ? si_p : 0.f;
        v[4] += p ? 0.f : si_p;
        v[5] += p ? sj_n : 0.f;
        v[6] += p ? sj_p : 0.f;
        v[7] += p ? 0.f : sj_p;
    }
    __shared__ float red[16][9];
    int wave = threadIdx.x >> 6, lane = threadIdx.x & 63;
    nt_s = wave_reduce_sum(nt_s);
#pragma unroll
    for (int i = 0; i < 8; ++i) v[i] = wave_reduce_sum(v[i]);
    if (lane == 0) {
        red[wave][0] = nt_s;
#pragma unroll
        for (int i = 0; i < 8; ++i) red[wave][1 + i] = v[i];
    }
    __syncthreads();
    if (threadIdx.x == 0) {
        float t[9];
#pragma unroll
        for (int i = 0; i < 9; ++i) {
            float acc = 0.f;
#pragma unroll
            for (int wv = 0; wv < 16; ++wv) acc += red[wv][i];
            t[i] = acc;
        }
        float ntxent = t[0] / (float)NROWS;
        float np = fmaxf(1.f, t[1]), nu = fmaxf(1.f, t[2]);
        float pr_i = PRIOR_PRIMEc / np * t[3];
        float nr_i = (1.f - PRIOR_PRIMEc) / (nu * (1.f - PRIORc)) * t[5]
                   - (1.f - PRIOR_PRIMEc) * PRIORc / (np * (1.f - PRIORc)) * t[4];
        float li_loss = (nr_i < 0.f) ? -nr_i : (pr_i + nr_i);
        float pr_j = PRIOR_PRIMEc / np * t[6];
        float nr_j = (1.f - PRIOR_PRIMEc) / (nu * (1.f - PRIORc)) * t[8]
                   - (1.f - PRIOR_PRIMEc) * PRIORc / (np * (1.f - PRIORc)) * t[7];
        float lj_loss = (nr_j < 0.f) ? -nr_j : (pr_j + nr_j);
        float onnpu = 0.5f * (li_loss + lj_loss);
        float w = w_onnpu[0];
        out[0] = w * onnpu + (1.f - w) * ntxent;
    }
}

extern "C" void kernel_launch(void* const* d_in, const int* in_sizes, int n_in,
                              void* d_out, int out_size, void* d_ws, size_t ws_size,
                              hipStream_t stream) {
    const float* h_i = (const float*)d_in[0];
    const float* h_j = (const float*)d_in[1];
    const float* z_i = (const float*)d_in[2];
    const float* z_j = (const float*)d_in[3];
    const int* target = (const int*)d_in[4];
    const float* W = (const float*)d_in[5];
    const float* b = (const float*)d_in[6];
    const float* w_onnpu = (const float*)d_in[7];

    char* ws = (char*)d_ws;
    unsigned short* znb = (unsigned short*)ws;                    // 2 MB swizzled bf16
    float* S_row   = (float*)(ws + 2097152);                      // 32 KB
    float* pos     = (float*)(ws + 2097152 + 32768);              // 32 KB
    float* logits  = (float*)(ws + 2097152 + 65536);              // 32 KB
    float* expdiag = (float*)(ws + 2097152 + 98304);              // 32 KB
    float* out = (float*)d_out;

    k_prep<<<3072, 256, 0, stream>>>(z_i, z_j, znb, pos, expdiag, S_row,
                                     h_i, h_j, W, b, logits);
    dim3 g(16, 64);
    k_sim<<<g, 256, 0, stream>>>(znb, S_row);
    k_final<<<1, 1024, 0, stream>>>(S_row, pos, expdiag, logits, target, w_onnpu, out);
}

// Round 8
// 151.346 us; speedup vs baseline: 1.0385x; 1.0385x over previous
//
#include <hip/hip_runtime.h>

#define BATCH  4096
#define NROWS  8192
#define LATENT 2048
#define ZDIM   128
#define PRIORc       0.3f
#define PRIOR_PRIMEc 0.5f
// sqrt(2 * log2(e)): folds both 1/TEMP and the ln->log2 conversion into zn,
// so exp(sim/TEMP) == exp2(dot of scaled vectors) -> bare v_exp_f32.
#define ZSCALE 1.6986436f

typedef __attribute__((ext_vector_type(8))) short bf16x8;  // 8 bf16 = 4 VGPRs
typedef __attribute__((ext_vector_type(4))) float f32x4;   // MFMA C/D + NT loads

__device__ inline unsigned short f2bf_rne(float f) {
    unsigned int u = __float_as_uint(f);
    u = u + 0x7fffu + ((u >> 16) & 1u);
    return (unsigned short)(u >> 16);
}
__device__ inline float bf2f(unsigned short h) {
    return __uint_as_float(((unsigned int)h) << 16);
}
__device__ inline float wave_reduce_sum(float v) {
#pragma unroll
    for (int m = 1; m < 64; m <<= 1) v += __shfl_xor(v, m, 64);
    return v;
}

// ---------------------------------------------------------------------------
// Node 1: blocks [0,1024) = z-prep (normalize+swizzle+pos+expdiag+S_row=0),
//         blocks [1024,3072) = logits (HBM-bound, NT loads).
// Disjoint writes, both read only inputs -> safe in one kernel, co-scheduled.
// Swizzle: chunk (g*4+kt), lane q*16+(row&15) holds k = kt*32+q*8 .. +7
// NOTE: no grid-wide fences anywhere — R5 showed __threadfence() from 3072
// blocks (L2 wb+inv) thrashes znb out of L2 (5x refetch, 136->520us).
// ---------------------------------------------------------------------------
__global__ void k_prep(const float* __restrict__ z_i, const float* __restrict__ z_j,
                       unsigned short* __restrict__ znb, float* __restrict__ pos,
                       float* __restrict__ expdiag, float* __restrict__ S_row,
                       const float* __restrict__ h_i, const float* __restrict__ h_j,
                       const float* __restrict__ W, const float* __restrict__ bb,
                       float* __restrict__ logits) {
    int bid = blockIdx.x;
    int wave = threadIdx.x >> 6, lane = threadIdx.x & 63;
    if (bid < 1024) {
        int gid = bid * 256 + threadIdx.x;
        if (gid < NROWS) S_row[gid] = 0.f;

        int r = bid * 4 + wave;               // 0..4095
        int p = r + BATCH;
        float2 a = ((const float2*)(z_i + (size_t)r * ZDIM))[lane];
        float2 c = ((const float2*)(z_j + (size_t)r * ZDIM))[lane];
        float sa = wave_reduce_sum(a.x * a.x + a.y * a.y);
        float sc = wave_reduce_sum(c.x * c.x + c.y * c.y);
        float dd = wave_reduce_sum(a.x * c.x + a.y * c.y);
        float inva = 1.f / fmaxf(sqrtf(sa), 1e-8f);
        float invc = 1.f / fmaxf(sqrtf(sc), 1e-8f);
        if (lane == 0) {
            float pv = 2.0f * dd * inva * invc;   // cos-sim / TEMP, exact fp32
            pos[r] = pv;
            pos[p] = pv;
        }
        int kt = lane >> 4;
        int q  = (lane >> 2) & 3;
        int j  = (lane & 3) * 2;
        int lrow = q * 16;
        float fa = inva * ZSCALE, fc = invc * ZSCALE;
        ushort2 wa, wc;
        wa.x = f2bf_rne(a.x * fa); wa.y = f2bf_rne(a.y * fa);
        wc.x = f2bf_rne(c.x * fc); wc.y = f2bf_rne(c.y * fc);
        {   // row r (from z_i)
            size_t off = ((size_t)((r >> 4) * 4 + kt) * 64 + (lrow + (r & 15))) * 8 + j;
            *(ushort2*)(znb + off) = wa;
        }
        {   // row p (from z_j)
            size_t off = ((size_t)((p >> 4) * 4 + kt) * 64 + (lrow + (p & 15))) * 8 + j;
            *(ushort2*)(znb + off) = wc;
        }
        // self-dot of the rounded values == MFMA diagonal (log2 domain)
        float xa = bf2f(wa.x), ya = bf2f(wa.y);
        float xc = bf2f(wc.x), yc = bf2f(wc.y);
        float sda = wave_reduce_sum(xa * xa + ya * ya);
        float sdc = wave_reduce_sum(xc * xc + yc * yc);
        if (lane == 0) {
            expdiag[r] = __builtin_amdgcn_exp2f(sda);
            expdiag[p] = __builtin_amdgcn_exp2f(sdc);
        }
    } else {
        int r = (bid - 1024) * 4 + wave;
        const float* h = (r < BATCH) ? (h_i + (size_t)r * LATENT)
                                     : (h_j + (size_t)(r - BATCH) * LATENT);
        const f32x4* h4 = (const f32x4*)h;
        const f32x4* w4 = (const f32x4*)W;
        float s = 0.f;
#pragma unroll
        for (int itr = 0; itr < 8; ++itr) {
            f32x4 av = __builtin_nontemporal_load(&h4[itr * 64 + lane]);
            f32x4 wv = w4[itr * 64 + lane];
            s += av.x * wv.x + av.y * wv.y + av.z * wv.z + av.w * wv.w;
        }
        s = wave_reduce_sum(s);
        if (lane == 0) logits[r] = s + bb[0];
    }
}

// ---------------------------------------------------------------------------
// Node 2: symmetric sim. Block (bx,by): rows [by*128,+128) x cols [bx*512,
// +512); skip if fully below diagonal. Each 16x16 subtile with g_c >= g_r
// computed once: row-sums in registers; transposed (col) contributions go to
// a per-block 512-entry LDS accumulator (LDS atomics are per-CU — R7's
// per-subtile GLOBAL atomics (2.1M onto 8K addrs) serialized at L2 and cost
// ~15us; now one coalesced flush of <=512 global atomics per block, ~280K
// total). Diagonal self term subtracted later via expdiag. B frags
// software-pipelined; literal-zero-C MFMA; bare exp2 epilogue.
// ---------------------------------------------------------------------------
__global__ void __launch_bounds__(256, 3) k_sim(const unsigned short* __restrict__ znb,
                                                float* __restrict__ S_row) {
    int bx = blockIdx.x, by = blockIdx.y;
    if (bx * 32 + 31 < by * 8) return;        // fully below diagonal
    __shared__ float colsum[512];
    colsum[threadIdx.x] = 0.f;
    colsum[threadIdx.x + 256] = 0.f;
    __syncthreads();

    int lane = threadIdx.x & 63, wave = threadIdx.x >> 6;
    int q = lane >> 4, t = lane & 15;
    int gA = by * 8 + (wave >> 1) * 4;        // abs 16-row group base (4 mt)
    int base16 = bx * 32 + (wave & 1) * 4;    // abs 16-col group base
    const bf16x8* zf = (const bf16x8*)znb;

    bf16x8 a[4][4];
#pragma unroll
    for (int mt = 0; mt < 4; ++mt)
#pragma unroll
        for (int kt = 0; kt < 4; ++kt)
            a[mt][kt] = zf[(size_t)((gA + mt) * 4 + kt) * 64 + lane];

    float s[16];
#pragma unroll
    for (int i = 0; i < 16; ++i) s[i] = 0.f;

    bf16x8 b[4];
#pragma unroll
    for (int kt = 0; kt < 4; ++kt)
        b[kt] = zf[(size_t)(base16 * 4 + kt) * 64 + lane];

    f32x4 zero = {0.f, 0.f, 0.f, 0.f};
#pragma unroll 1
    for (int idx = 0; idx < 16; ++idx) {
        int g_c = base16 + (idx >> 2) * 8 + (idx & 3);
        bf16x8 bn[4];
        if (idx < 15) {
            int ng = base16 + ((idx + 1) >> 2) * 8 + ((idx + 1) & 3);
#pragma unroll
            for (int kt = 0; kt < 4; ++kt)
                bn[kt] = zf[(size_t)(ng * 4 + kt) * 64 + lane];
        }
        if (g_c >= gA) {                      // wave-uniform
            f32x4 acc[4];
#pragma unroll
            for (int mt = 0; mt < 4; ++mt)    // kt=0 consumes literal-zero C
                acc[mt] = __builtin_amdgcn_mfma_f32_16x16x32_bf16(a[mt][0], b[0], zero, 0, 0, 0);
#pragma unroll
            for (int kt = 1; kt < 4; ++kt)
#pragma unroll
                for (int mt = 0; mt < 4; ++mt)
                    acc[mt] = __builtin_amdgcn_mfma_f32_16x16x32_bf16(a[mt][kt], b[kt], acc[mt], 0, 0, 0);
            float ecol = 0.f;
#pragma unroll
            for (int mt = 0; mt < 4; ++mt) {
                bool rowv = (g_c >= gA + mt);
                bool colv = (g_c >  gA + mt);
                float em = 0.f;
#pragma unroll
                for (int reg = 0; reg < 4; ++reg) {
                    float e = __builtin_amdgcn_exp2f(acc[mt][reg]);
                    s[mt * 4 + reg] += rowv ? e : 0.f;
                    em += e;
                }
                ecol += colv ? em : 0.f;
            }
            if (g_c > gA) {                   // transposed contribution -> LDS
                ecol += __shfl_xor(ecol, 16, 64);
                ecol += __shfl_xor(ecol, 32, 64);
                if (lane < 16)
                    atomicAdd(&colsum[(g_c - bx * 32) * 16 + lane], ecol);
            }
        }
#pragma unroll
        for (int kt = 0; kt < 4; ++kt) b[kt] = bn[kt];
    }
    // row sums: register -> shuffle-reduce -> one global atomic per row
#pragma unroll
    for (int i = 0; i < 16; ++i) {
        float v = s[i];
        v += __shfl_xor(v, 1, 64);
        v += __shfl_xor(v, 2, 64);
        v += __shfl_xor(v, 4, 64);
        v += __shfl_xor(v, 8, 64);
        if (t == 0) atomicAdd(&S_row[gA * 16 + (i >> 2) * 16 + q * 4 + (i & 3)], v);
    }
    // col sums: one coalesced flush per block, skip zero (dead) entries
    __syncthreads();
#pragma unroll
    for (int k = 0; k < 2; ++k) {
        int local = threadIdx.x + k * 256;
        float v = colsum[local];
        if (v != 0.f) atomicAdd(&S_row[bx * 512 + local], v);
    }
}

// Node 3: nnPU risk from logits+target, NT-Xent from S_row (minus the
// bf16-exact diagonal term) + pos, weighted combine.
__global__ void k_final(const float* __restrict__ S_row, const float* __restrict__ pos,
                        const float* __restrict__ expdiag,
                        const float* __restrict__ logits, const int* __restrict__ target,
                        const float* __restrict__ w_onnpu, float* __restrict__ out) {
    float nt_s = 0.f;
    for (int r = threadIdx.x; r < NROWS; r += 1024)
        nt_s += __logf(S_row[r] - expdiag[r]) - pos[r];
    float v[8];
#pragma unroll
    for (int i = 0; i < 8; ++i) v[i] = 0.f;
    for (int r = threadIdx.x; r < BATCH; r += 1024) {
        float li = logits[r], lj = logits[BATCH + r];
        bool p = (target[r] == 1);
        float si_n = 1.f / (1.f + __expf(li));
        float si_p = 1.f / (1.f + __expf(-li));
        float sj_n = 1.f / (1.f + __expf(lj));
        float sj_p = 1.f / (1.f + __expf(-lj));
        v[0] += p ? 1.f : 0.f;
        v[1] += p ? 0.f : 1.f;
        v[2] += p ? si_n : 0.f;
        v[3] += p ? si_p : 0.f;
        v[4] += p ? 0.f : si_p;
        v[5] += p ? sj_n : 0.f;
        v[6] += p ? sj_p : 0.f;
        v[7] += p ? 0.f : sj_p;
    }
    __shared__ float red[16][9];
    int wave = threadIdx.x >> 6, lane = threadIdx.x & 63;
    nt_s = wave_reduce_sum(nt_s);
#pragma unroll
    for (int i = 0; i < 8; ++i) v[i] = wave_reduce_sum(v[i]);
    if (lane == 0) {
        red[wave][0] = nt_s;
#pragma unroll
        for (int i = 0; i < 8; ++i) red[wave][1 + i] = v[i];
    }
    __syncthreads();
    if (threadIdx.x == 0) {
        float t[9];
#pragma unroll
        for (int i = 0; i < 9; ++i) {
            float acc = 0.f;
#pragma unroll
            for (int wv = 0; wv < 16; ++wv) acc += red[wv][i];
            t[i] = acc;
        }
        float ntxent = t[0] / (float)NROWS;
        float np = fmaxf(1.f, t[1]), nu = fmaxf(1.f, t[2]);
        float pr_i = PRIOR_PRIMEc / np * t[3];
        float nr_i = (1.f - PRIOR_PRIMEc) / (nu * (1.f - PRIORc)) * t[5]
                   - (1.f - PRIOR_PRIMEc) * PRIORc / (np * (1.f - PRIORc)) * t[4];
        float li_loss = (nr_i < 0.f) ? -nr_i : (pr_i + nr_i);
        float pr_j = PRIOR_PRIMEc / np * t[6];
        float nr_j = (1.f - PRIOR_PRIMEc) / (nu * (1.f - PRIORc)) * t[8]
                   - (1.f - PRIOR_PRIMEc) * PRIORc / (np * (1.f - PRIORc)) * t[7];
        float lj_loss = (nr_j < 0.f) ? -nr_j : (pr_j + nr_j);
        float onnpu = 0.5f * (li_loss + lj_loss);
        float w = w_onnpu[0];
        out[0] = w * onnpu + (1.f - w) * ntxent;
    }
}

extern "C" void kernel_launch(void* const* d_in, const int* in_sizes, int n_in,
                              void* d_out, int out_size, void* d_ws, size_t ws_size,
                              hipStream_t stream) {
    const float* h_i = (const float*)d_in[0];
    const float* h_j = (const float*)d_in[1];
    const float* z_i = (const float*)d_in[2];
    const float* z_j = (const float*)d_in[3];
    const int* target = (const int*)d_in[4];
    const float* W = (const float*)d_in[5];
    const float* b = (const float*)d_in[6];
    const float* w_onnpu = (const float*)d_in[7];

    char* ws = (char*)d_ws;
    unsigned short* znb = (unsigned short*)ws;                    // 2 MB swizzled bf16
    float* S_row   = (float*)(ws + 2097152);                      // 32 KB
    float* pos     = (float*)(ws + 2097152 + 32768);              // 32 KB
    float* logits  = (float*)(ws + 2097152 + 65536);              // 32 KB
    float* expdiag = (float*)(ws + 2097152 + 98304);              // 32 KB
    float* out = (float*)d_out;

    k_prep<<<3072, 256, 0, stream>>>(z_i, z_j, znb, pos, expdiag, S_row,
                                     h_i, h_j, W, b, logits);
    dim3 g(16, 64);
    k_sim<<<g, 256, 0, stream>>>(znb, S_row);
    k_final<<<1, 1024, 0, stream>>>(S_row, pos, expdiag, logits, target, w_onnpu, out);
}